// Round 24
// baseline (110.872 us; speedup 1.0000x reference)
//
#include <hip/hip_runtime.h>
#include <hip/hip_bf16.h>
#include <cstdint>
#include <cstddef>

typedef short bf16x8 __attribute__((ext_vector_type(8)));
typedef float f32x16 __attribute__((ext_vector_type(16)));
typedef unsigned int uint2v __attribute__((ext_vector_type(2)));

// 2^x — COMPILER-VISIBLE builtin (hazard recognizer inserts MFMA->VALU
// wait states; inline-asm v_exp_f32 reading an MFMA dst adjacently was
// the R22 corruption). Compiles to one v_exp_f32 (R13).
#if __has_builtin(__builtin_amdgcn_exp2f)
#define EXP2F(x) __builtin_amdgcn_exp2f(x)
#else
#define EXP2F(x) exp2f(x)
#endif

// scale^2 * log2(e) folded into Q; ch=64 -> (1/8)*1.4426950408889634
#define QSCALE 0.18033688011112043f

__device__ __forceinline__ short f2bf(float f) {
  union { __hip_bfloat16 b; short s; } u;
  u.b = __float2bfloat16(f);
  return u.s;
}

// packed f32x2 -> bf16x2 RNE (compiles to v_cvt_pk_bf16_f32)
__device__ __forceinline__ unsigned int packbf2(float a, float b) {
  union { __hip_bfloat162 h; unsigned int w; } u;
  u.h = __float22bfloat162_rn(float2{a, b});
  return u.w;
}

__device__ __forceinline__ unsigned int fbits(float f) {
  union { float f; unsigned int u; } x; x.f = f; return x.u;
}
__device__ __forceinline__ float bfloat(unsigned int u) {
  union { unsigned int u; float f; } x; x.u = u; return x.f;
}

// permlane32_swap builtin — ONLY for commutative own+partner combines
// (order-invariant; per-word routing through it falsified R8/R19)
__device__ __forceinline__ float fadd_x32(float v) {
  const uint2v r = __builtin_amdgcn_permlane32_swap(fbits(v), fbits(v),
                                                    false, false);
  return bfloat(r[0]) + bfloat(r[1]);
}

// async global -> LDS, 16 B per lane; LDS dest = wave-uniform base + lane*16
__device__ __forceinline__ void gload16(const short* g, char* l) {
  __builtin_amdgcn_global_load_lds(
      (const __attribute__((address_space(1))) void*)g,
      (__attribute__((address_space(3))) void*)l, 16, 0, 0);
}

// ---------------------------------------------------------------------------
// Prepass: Kt[bh][s][c] = bf16(K[c][s]);  Vb[bh][c][s] = bf16(V[c][s]).
// qkv layout: [bh][cc][t], cc: 0..63 Q, 64..127 K, 128..191 V.
// ---------------------------------------------------------------------------
__global__ __launch_bounds__(256, 4) void qkv_prep_kernel(
    const float* __restrict__ qkv, short* __restrict__ Kt,
    short* __restrict__ Vb) {
  const int bh = blockIdx.x >> 5;
  const int s0 = (blockIdx.x & 31) << 6;
  const int tid = threadIdx.x;
  const int row = tid >> 2;   // 0..63
  const int part = tid & 3;   // 0..3  (16 columns each)
  __shared__ float lds[64 * 65];

  const size_t qb = (size_t)bh * (192 * 2048);

  // ---- K: load [c][s] tile coalesced into LDS ----
  {
    const float* src = qkv + qb + (size_t)(64 + row) * 2048 + s0 + part * 16;
#pragma unroll
    for (int k4 = 0; k4 < 4; ++k4) {
      float4 v = ((const float4*)src)[k4];
      float* p = &lds[row * 65 + part * 16 + k4 * 4];
      p[0] = v.x; p[1] = v.y; p[2] = v.z; p[3] = v.w;
    }
  }
  __syncthreads();
  // ---- transposed read -> Kt[s][c], coalesced 16B stores ----
  {
    bf16x8 o0, o1;
#pragma unroll
    for (int k = 0; k < 8; ++k) o0[k] = f2bf(lds[(part * 16 + k) * 65 + row]);
#pragma unroll
    for (int k = 0; k < 8; ++k) o1[k] = f2bf(lds[(part * 16 + 8 + k) * 65 + row]);
    short* dst = Kt + ((size_t)bh * 2048 + s0 + row) * 64 + part * 16;
    *(bf16x8*)dst = o0;
    *(bf16x8*)(dst + 8) = o1;
  }
  // ---- V: straight convert, both sides coalesced ----
  {
    const float* src = qkv + qb + (size_t)(128 + row) * 2048 + s0 + part * 16;
    float a[16];
#pragma unroll
    for (int k4 = 0; k4 < 4; ++k4) {
      float4 v = ((const float4*)src)[k4];
      a[k4 * 4 + 0] = v.x; a[k4 * 4 + 1] = v.y;
      a[k4 * 4 + 2] = v.z; a[k4 * 4 + 3] = v.w;
    }
    bf16x8 o0, o1;
#pragma unroll
    for (int k = 0; k < 8; ++k) { o0[k] = f2bf(a[k]); o1[k] = f2bf(a[8 + k]); }
    short* dst = Vb + ((size_t)bh * 64 + row) * 2048 + s0 + part * 16;
    *(bf16x8*)dst = o0;
    *(bf16x8*)(dst + 8) = o1;
  }
}

// ---------------------------------------------------------------------------
// Flash attention (fixed-shift softmax), fully MFMA/VALU-adjacent body:
//   QK_0 ; [SM_0 + pack_0] ; QK_1 ; PV_0 ; [SM_1 + pack_1] ; PV_1
// The entire SM_0+pack_0 VALU/DS train (16 exp2 + 8 cvt_pk + 2 shfl) is
// independent of QK_1's 4 MFMAs; SM_1+pack_1 independent of PV_0 -> the
// scheduler co-issues across pipes within the wave (R23-verified lever,
// extended: pack moved adjacent to its SM). pa[0..1] live across QK_1 =
// +4 VGPR only. exp2 via compiler-visible builtin (R22 hazard lesson).
// Everything else R17/R20-verified: 512 blocks XCD-swizzled, 8 waves,
// 32 t/wave; 64-s chunks; K/V LDS dbuf; gload_lds pre-swizzled source;
// ONE __syncthreads per chunk; setprio around MFMA clusters.
// ---------------------------------------------------------------------------
__global__ __launch_bounds__(512, 4) void attn32_kernel(
    const float* __restrict__ qkv, const short* __restrict__ Kt,
    const short* __restrict__ Vb, float* __restrict__ out) {
  const int bid = blockIdx.x;
  const int vid = (bid & 7) * 64 + (bid >> 3);  // bijective XCD swizzle (512)
  const int bh = vid >> 3;
  const int tblk = vid & 7;
  const int tid = threadIdx.x;
  const int wv = tid >> 6;          // 0..7
  const int lane = tid & 63;
  const int tl = lane & 31;
  const int hi = lane >> 5;
  const int t0w = tblk * 256 + wv * 32;

  // [buf0: K 8K | V 8K][buf1: K 8K | V 8K]
  __shared__ __align__(16) char smem[32768];

  // ---- Q fragments (B-operand: col = t = lane&31, k = kc*16 + hi*8 + j) ----
  const size_t qb = (size_t)bh * (192 * 2048);
  bf16x8 qf[4];
#pragma unroll
  for (int kc = 0; kc < 4; ++kc) {
#pragma unroll
    for (int j = 0; j < 8; ++j) {
      const int c = kc * 16 + hi * 8 + j;
      qf[kc][j] = f2bf(qkv[qb + (size_t)c * 2048 + t0w + tl] * QSCALE);
    }
  }

  // persistent zero C-operand (avoids per-chunk zero-init movs)
  f32x16 zv;
#pragma unroll
  for (int r = 0; r < 16; ++r) zv[r] = 0.f;

  f32x16 acc[2];
#pragma unroll
  for (int cb = 0; cb < 2; ++cb) acc[cb] = zv;

  float lsum = 0.f;

  // ---- hoisted LDS read offsets: one table serves QK (rows=s) and PV
  // (rows=c): off[x][j] = (x*32+tl)*128 + ((j*32+hi*16) ^ rsw) ----
  const int rsw = (tl & 7) * 16;
  int off[2][4];
#pragma unroll
  for (int x = 0; x < 2; ++x)
#pragma unroll
    for (int j = 0; j < 4; ++j)
      off[x][j] = (x * 32 + tl) * 128 + ((j * 32 + hi * 16) ^ rsw);

  // ---- staging geometry: 512 threads cover all 64 rows in one pass ----
  const int srow = tid >> 3;   // 0..63
  const int sl = tid & 7;      // 16B slot within 128B row
  // pre-swizzled global sources (slot ^ (row&7)); involution matches reads
  const short* kg = Kt + (size_t)bh * (2048 * 64) + (size_t)srow * 64 +
                    ((sl ^ (srow & 7)) * 8);
  const short* vg = Vb + ((size_t)bh * 64 + srow) * 2048 +
                    ((sl ^ (srow & 7)) * 8);
  // wave-uniform LDS byte offset (lane*16 added by HW):
  // wave wv covers rows [wv*8, wv*8+8): base = wv*8*128 = wv*1024
  const int ldb = wv * 1024;

  // ---- prologue: stage chunk 0 into buf0 ----
  gload16(kg, smem + ldb);
  gload16(vg, smem + 8192 + ldb);

#pragma unroll 2
  for (int ch = 0; ch < 32; ++ch) {
    char* const Kls = smem + (ch & 1) * 16384;
    char* const Vls = Kls + 8192;

    // barrier: (a) all waves done reading buf^1, (b) vmcnt(0) inside the
    // barrier drains this chunk's prefetch -> buf ready
    __syncthreads();

    // ---- issue next chunk's staging; flies under this chunk's compute ----
    if (ch < 31) {
      char* const Knx = smem + ((ch + 1) & 1) * 16384;
      gload16(kg + (size_t)(ch + 1) * 4096, Knx + ldb);        // 64 rows x 64c
      gload16(vg + (ch + 1) * 64, Knx + 8192 + ldb);           // 64 s along row
    }

    f32x16 lg[2];
    bf16x8 pa[4];

    // ---- QK_0: s-tile 0 (rows 0..31) ----
    __builtin_amdgcn_s_setprio(1);
    {
      bf16x8 ka = *(const bf16x8*)(Kls + off[0][0]);
      lg[0] = __builtin_amdgcn_mfma_f32_32x32x16_bf16(ka, qf[0], zv, 0, 0, 0);
#pragma unroll
      for (int kc = 1; kc < 4; ++kc) {
        ka = *(const bf16x8*)(Kls + off[0][kc]);
        lg[0] = __builtin_amdgcn_mfma_f32_32x32x16_bf16(ka, qf[kc], lg[0],
                                                        0, 0, 0);
      }
    }
    __builtin_amdgcn_s_setprio(0);

    // ---- SM_0 + pack_0: full VALU train, independent of QK_1 below ----
    float ps0 = 0.f;
#pragma unroll
    for (int r = 0; r < 16; ++r) lg[0][r] = EXP2F(lg[0][r]);
#pragma unroll
    for (int r = 0; r < 8; ++r) ps0 += lg[0][2 * r] + lg[0][2 * r + 1];
    lsum += ps0;
#pragma unroll
    for (int kl = 0; kl < 2; ++kl) {
      const unsigned int p0a = packbf2(lg[0][8 * kl + 0], lg[0][8 * kl + 1]);
      const unsigned int p0b = packbf2(lg[0][8 * kl + 2], lg[0][8 * kl + 3]);
      const unsigned int p1a = packbf2(lg[0][8 * kl + 4], lg[0][8 * kl + 5]);
      const unsigned int p1b = packbf2(lg[0][8 * kl + 6], lg[0][8 * kl + 7]);
      const unsigned int sa = hi ? p0a : p1a;
      const unsigned int sb = hi ? p0b : p1b;
      const unsigned int ra = __shfl_xor(sa, 32);
      const unsigned int rb = __shfl_xor(sb, 32);
      union { unsigned int w[4]; bf16x8 v; } u;
      u.w[0] = hi ? ra : p0a;
      u.w[1] = hi ? rb : p0b;
      u.w[2] = hi ? p1a : ra;
      u.w[3] = hi ? p1b : rb;
      pa[kl] = u.v;
    }

    // ---- QK_1: s-tile 1 (rows 32..63), overlaps SM_0+pack_0 ----
    __builtin_amdgcn_s_setprio(1);
    {
      bf16x8 ka = *(const bf16x8*)(Kls + off[1][0]);
      lg[1] = __builtin_amdgcn_mfma_f32_32x32x16_bf16(ka, qf[0], zv, 0, 0, 0);
#pragma unroll
      for (int kc = 1; kc < 4; ++kc) {
        ka = *(const bf16x8*)(Kls + off[1][kc]);
        lg[1] = __builtin_amdgcn_mfma_f32_32x32x16_bf16(ka, qf[kc], lg[1],
                                                        0, 0, 0);
      }
    }

    // ---- PV_0 (ks 0..1) ----
#pragma unroll
    for (int cb = 0; cb < 2; ++cb) {
#pragma unroll
      for (int ks = 0; ks < 2; ++ks) {
        const bf16x8 vb = *(const bf16x8*)(Vls + off[cb][ks]);
        acc[cb] = __builtin_amdgcn_mfma_f32_32x32x16_bf16(vb, pa[ks], acc[cb],
                                                          0, 0, 0);
      }
    }
    __builtin_amdgcn_s_setprio(0);

    // ---- SM_1 + pack_1: independent of PV_0 above -> co-issue ----
    float ps1 = 0.f;
#pragma unroll
    for (int r = 0; r < 16; ++r) lg[1][r] = EXP2F(lg[1][r]);
#pragma unroll
    for (int r = 0; r < 8; ++r) ps1 += lg[1][2 * r] + lg[1][2 * r + 1];
    lsum += ps1;
#pragma unroll
    for (int kl = 0; kl < 2; ++kl) {
      const unsigned int p0a = packbf2(lg[1][8 * kl + 0], lg[1][8 * kl + 1]);
      const unsigned int p0b = packbf2(lg[1][8 * kl + 2], lg[1][8 * kl + 3]);
      const unsigned int p1a = packbf2(lg[1][8 * kl + 4], lg[1][8 * kl + 5]);
      const unsigned int p1b = packbf2(lg[1][8 * kl + 6], lg[1][8 * kl + 7]);
      const unsigned int sa = hi ? p0a : p1a;
      const unsigned int sb = hi ? p0b : p1b;
      const unsigned int ra = __shfl_xor(sa, 32);
      const unsigned int rb = __shfl_xor(sb, 32);
      union { unsigned int w[4]; bf16x8 v; } u;
      u.w[0] = hi ? ra : p0a;
      u.w[1] = hi ? rb : p0b;
      u.w[2] = hi ? p1a : ra;
      u.w[3] = hi ? p1b : rb;
      pa[2 + kl] = u.v;
    }

    // ---- PV_1 (ks 2..3) ----
    __builtin_amdgcn_s_setprio(1);
#pragma unroll
    for (int cb = 0; cb < 2; ++cb) {
#pragma unroll
      for (int ks = 2; ks < 4; ++ks) {
        const bf16x8 vb = *(const bf16x8*)(Vls + off[cb][ks]);
        acc[cb] = __builtin_amdgcn_mfma_f32_32x32x16_bf16(vb, pa[ks], acc[cb],
                                                          0, 0, 0);
      }
    }
    __builtin_amdgcn_s_setprio(0);
  }

  // ---- epilogue: normalize + store (D: col=t=lane&31, row=c) ----
  const float ls = fadd_x32(lsum);
  const float inv = 1.0f / ls;
#pragma unroll
  for (int cb = 0; cb < 2; ++cb) {
#pragma unroll
    for (int r = 0; r < 16; ++r) {
      const int c = cb * 32 + (r & 3) + 8 * (r >> 2) + 4 * hi;
      out[((size_t)bh * 64 + c) * 2048 + t0w + tl] = acc[cb][r] * inv;
    }
  }
}

extern "C" void kernel_launch(void* const* d_in, const int* in_sizes, int n_in,
                              void* d_out, int out_size, void* d_ws,
                              size_t ws_size, hipStream_t stream) {
  (void)in_sizes; (void)n_in; (void)out_size;
  const float* qkv = (const float*)d_in[0];
  float* out = (float*)d_out;
  const size_t kv_elems = (size_t)64 * 2048 * 64;
  if (ws_size < kv_elems * 2 * sizeof(short)) return;  // need 32 MB scratch
  short* Kt = (short*)d_ws;
  short* Vb = Kt + kv_elems;
  hipLaunchKernelGGL(qkv_prep_kernel, dim3(2048), dim3(256), 0, stream,
                     qkv, Kt, Vb);
  hipLaunchKernelGGL(attn32_kernel, dim3(512), dim3(512), 0, stream,
                     qkv, Kt, Vb, out);
}

// Round 25
// 107.329 us; speedup vs baseline: 1.0330x; 1.0330x over previous
//
#include <hip/hip_runtime.h>
#include <hip/hip_bf16.h>
#include <cstdint>
#include <cstddef>

typedef short bf16x8 __attribute__((ext_vector_type(8)));
typedef float f32x16 __attribute__((ext_vector_type(16)));
typedef unsigned int uint2v __attribute__((ext_vector_type(2)));

// 2^x — COMPILER-VISIBLE builtin (hazard recognizer inserts MFMA->VALU
// wait states; inline-asm v_exp_f32 reading an MFMA dst adjacently was
// the R22 corruption — rule #18 family). Compiles to one v_exp_f32 (R13).
#if __has_builtin(__builtin_amdgcn_exp2f)
#define EXP2F(x) __builtin_amdgcn_exp2f(x)
#else
#define EXP2F(x) exp2f(x)
#endif

// scale^2 * log2(e) folded into Q; ch=64 -> (1/8)*1.4426950408889634
#define QSCALE 0.18033688011112043f

__device__ __forceinline__ short f2bf(float f) {
  union { __hip_bfloat16 b; short s; } u;
  u.b = __float2bfloat16(f);
  return u.s;
}

// packed f32x2 -> bf16x2 RNE (compiles to v_cvt_pk_bf16_f32)
__device__ __forceinline__ unsigned int packbf2(float a, float b) {
  union { __hip_bfloat162 h; unsigned int w; } u;
  u.h = __float22bfloat162_rn(float2{a, b});
  return u.w;
}

__device__ __forceinline__ unsigned int fbits(float f) {
  union { float f; unsigned int u; } x; x.f = f; return x.u;
}
__device__ __forceinline__ float bfloat(unsigned int u) {
  union { unsigned int u; float f; } x; x.u = u; return x.f;
}

// permlane32_swap builtin — ONLY for commutative own+partner combines
// (order-invariant; per-word routing through it falsified R8/R19)
__device__ __forceinline__ float fadd_x32(float v) {
  const uint2v r = __builtin_amdgcn_permlane32_swap(fbits(v), fbits(v),
                                                    false, false);
  return bfloat(r[0]) + bfloat(r[1]);
}

// async global -> LDS, 16 B per lane; LDS dest = wave-uniform base + lane*16
__device__ __forceinline__ void gload16(const short* g, char* l) {
  __builtin_amdgcn_global_load_lds(
      (const __attribute__((address_space(1))) void*)g,
      (__attribute__((address_space(3))) void*)l, 16, 0, 0);
}

// ---------------------------------------------------------------------------
// Prepass: Kt[bh][s][c] = bf16(K[c][s]);  Vb[bh][c][s] = bf16(V[c][s]).
// qkv layout: [bh][cc][t], cc: 0..63 Q, 64..127 K, 128..191 V.
// ---------------------------------------------------------------------------
__global__ __launch_bounds__(256, 4) void qkv_prep_kernel(
    const float* __restrict__ qkv, short* __restrict__ Kt,
    short* __restrict__ Vb) {
  const int bh = blockIdx.x >> 5;
  const int s0 = (blockIdx.x & 31) << 6;
  const int tid = threadIdx.x;
  const int row = tid >> 2;   // 0..63
  const int part = tid & 3;   // 0..3  (16 columns each)
  __shared__ float lds[64 * 65];

  const size_t qb = (size_t)bh * (192 * 2048);

  // ---- K: load [c][s] tile coalesced into LDS ----
  {
    const float* src = qkv + qb + (size_t)(64 + row) * 2048 + s0 + part * 16;
#pragma unroll
    for (int k4 = 0; k4 < 4; ++k4) {
      float4 v = ((const float4*)src)[k4];
      float* p = &lds[row * 65 + part * 16 + k4 * 4];
      p[0] = v.x; p[1] = v.y; p[2] = v.z; p[3] = v.w;
    }
  }
  __syncthreads();
  // ---- transposed read -> Kt[s][c], coalesced 16B stores ----
  {
    bf16x8 o0, o1;
#pragma unroll
    for (int k = 0; k < 8; ++k) o0[k] = f2bf(lds[(part * 16 + k) * 65 + row]);
#pragma unroll
    for (int k = 0; k < 8; ++k) o1[k] = f2bf(lds[(part * 16 + 8 + k) * 65 + row]);
    short* dst = Kt + ((size_t)bh * 2048 + s0 + row) * 64 + part * 16;
    *(bf16x8*)dst = o0;
    *(bf16x8*)(dst + 8) = o1;
  }
  // ---- V: straight convert, both sides coalesced ----
  {
    const float* src = qkv + qb + (size_t)(128 + row) * 2048 + s0 + part * 16;
    float a[16];
#pragma unroll
    for (int k4 = 0; k4 < 4; ++k4) {
      float4 v = ((const float4*)src)[k4];
      a[k4 * 4 + 0] = v.x; a[k4 * 4 + 1] = v.y;
      a[k4 * 4 + 2] = v.z; a[k4 * 4 + 3] = v.w;
    }
    bf16x8 o0, o1;
#pragma unroll
    for (int k = 0; k < 8; ++k) { o0[k] = f2bf(a[k]); o1[k] = f2bf(a[8 + k]); }
    short* dst = Vb + ((size_t)bh * 64 + row) * 2048 + s0 + part * 16;
    *(bf16x8*)dst = o0;
    *(bf16x8*)(dst + 8) = o1;
  }
}

// ---------------------------------------------------------------------------
// Flash attention (fixed-shift softmax) with MFMA/VALU-adjacent body
// (R23-verified best: 107.7 µs, steady ~103):
//   QK_0 ; SM_0 ; QK_1 ; pack_0+PV_0 ; SM_1 ; pack_1+PV_1
// SM_0 (exp2/TRANS) independent of QK_1 (MFMA+ds_read); SM_1 independent
// of PV_0 -> cross-pipe co-issue within the wave. exp2 via the
// compiler-visible builtin (R22 inline-asm hazard lesson). R24's further
// pack-hoist regressed (~+5 µs) — this ordering is the optimum found.
// Everything else verified: 512 blocks XCD-swizzled, 8 waves, 32 t/wave;
// 64-s chunks; K/V LDS dbuf; gload_lds pre-swizzled source (G21); ONE
// __syncthreads per chunk; setprio around MFMA clusters (T5).
// ---------------------------------------------------------------------------
__global__ __launch_bounds__(512, 4) void attn32_kernel(
    const float* __restrict__ qkv, const short* __restrict__ Kt,
    const short* __restrict__ Vb, float* __restrict__ out) {
  const int bid = blockIdx.x;
  const int vid = (bid & 7) * 64 + (bid >> 3);  // bijective XCD swizzle (512)
  const int bh = vid >> 3;
  const int tblk = vid & 7;
  const int tid = threadIdx.x;
  const int wv = tid >> 6;          // 0..7
  const int lane = tid & 63;
  const int tl = lane & 31;
  const int hi = lane >> 5;
  const int t0w = tblk * 256 + wv * 32;

  // [buf0: K 8K | V 8K][buf1: K 8K | V 8K]
  __shared__ __align__(16) char smem[32768];

  // ---- Q fragments (B-operand: col = t = lane&31, k = kc*16 + hi*8 + j) ----
  const size_t qb = (size_t)bh * (192 * 2048);
  bf16x8 qf[4];
#pragma unroll
  for (int kc = 0; kc < 4; ++kc) {
#pragma unroll
    for (int j = 0; j < 8; ++j) {
      const int c = kc * 16 + hi * 8 + j;
      qf[kc][j] = f2bf(qkv[qb + (size_t)c * 2048 + t0w + tl] * QSCALE);
    }
  }

  // persistent zero C-operand (avoids per-chunk zero-init movs)
  f32x16 zv;
#pragma unroll
  for (int r = 0; r < 16; ++r) zv[r] = 0.f;

  f32x16 acc[2];
#pragma unroll
  for (int cb = 0; cb < 2; ++cb) acc[cb] = zv;

  float lsum = 0.f;

  // ---- hoisted LDS read offsets: one table serves QK (rows=s) and PV
  // (rows=c): off[x][j] = (x*32+tl)*128 + ((j*32+hi*16) ^ rsw) ----
  const int rsw = (tl & 7) * 16;
  int off[2][4];
#pragma unroll
  for (int x = 0; x < 2; ++x)
#pragma unroll
    for (int j = 0; j < 4; ++j)
      off[x][j] = (x * 32 + tl) * 128 + ((j * 32 + hi * 16) ^ rsw);

  // ---- staging geometry: 512 threads cover all 64 rows in one pass ----
  const int srow = tid >> 3;   // 0..63
  const int sl = tid & 7;      // 16B slot within 128B row
  // pre-swizzled global sources (slot ^ (row&7)); involution matches reads
  const short* kg = Kt + (size_t)bh * (2048 * 64) + (size_t)srow * 64 +
                    ((sl ^ (srow & 7)) * 8);
  const short* vg = Vb + ((size_t)bh * 64 + srow) * 2048 +
                    ((sl ^ (srow & 7)) * 8);
  // wave-uniform LDS byte offset (lane*16 added by HW):
  // wave wv covers rows [wv*8, wv*8+8): base = wv*8*128 = wv*1024
  const int ldb = wv * 1024;

  // ---- prologue: stage chunk 0 into buf0 ----
  gload16(kg, smem + ldb);
  gload16(vg, smem + 8192 + ldb);

#pragma unroll 2
  for (int ch = 0; ch < 32; ++ch) {
    char* const Kls = smem + (ch & 1) * 16384;
    char* const Vls = Kls + 8192;

    // barrier: (a) all waves done reading buf^1, (b) vmcnt(0) inside the
    // barrier drains this chunk's prefetch -> buf ready
    __syncthreads();

    // ---- issue next chunk's staging; flies under this chunk's compute ----
    if (ch < 31) {
      char* const Knx = smem + ((ch + 1) & 1) * 16384;
      gload16(kg + (size_t)(ch + 1) * 4096, Knx + ldb);        // 64 rows x 64c
      gload16(vg + (ch + 1) * 64, Knx + 8192 + ldb);           // 64 s along row
    }

    f32x16 lg[2];
    bf16x8 pa[4];

    // ---- QK_0: s-tile 0 (rows 0..31) ----
    __builtin_amdgcn_s_setprio(1);
    {
      bf16x8 ka = *(const bf16x8*)(Kls + off[0][0]);
      lg[0] = __builtin_amdgcn_mfma_f32_32x32x16_bf16(ka, qf[0], zv, 0, 0, 0);
#pragma unroll
      for (int kc = 1; kc < 4; ++kc) {
        ka = *(const bf16x8*)(Kls + off[0][kc]);
        lg[0] = __builtin_amdgcn_mfma_f32_32x32x16_bf16(ka, qf[kc], lg[0],
                                                        0, 0, 0);
      }
    }
    __builtin_amdgcn_s_setprio(0);

    // ---- SM_0: exp2 on lg[0] (independent of QK_1 below -> co-issue) ----
    float ps0 = 0.f;
#pragma unroll
    for (int r = 0; r < 16; ++r) lg[0][r] = EXP2F(lg[0][r]);
#pragma unroll
    for (int r = 0; r < 8; ++r) ps0 += lg[0][2 * r] + lg[0][2 * r + 1];
    lsum += ps0;

    // ---- QK_1: s-tile 1 (rows 32..63), overlaps SM_0's TRANS chain ----
    __builtin_amdgcn_s_setprio(1);
    {
      bf16x8 ka = *(const bf16x8*)(Kls + off[1][0]);
      lg[1] = __builtin_amdgcn_mfma_f32_32x32x16_bf16(ka, qf[0], zv, 0, 0, 0);
#pragma unroll
      for (int kc = 1; kc < 4; ++kc) {
        ka = *(const bf16x8*)(Kls + off[1][kc]);
        lg[1] = __builtin_amdgcn_mfma_f32_32x32x16_bf16(ka, qf[kc], lg[1],
                                                        0, 0, 0);
      }
    }
    __builtin_amdgcn_s_setprio(0);

    // ---- pack_0 + PV_0 (ks 0..1), overlapped below by SM_1 ----
#pragma unroll
    for (int kl = 0; kl < 2; ++kl) {
      const unsigned int p0a = packbf2(lg[0][8 * kl + 0], lg[0][8 * kl + 1]);
      const unsigned int p0b = packbf2(lg[0][8 * kl + 2], lg[0][8 * kl + 3]);
      const unsigned int p1a = packbf2(lg[0][8 * kl + 4], lg[0][8 * kl + 5]);
      const unsigned int p1b = packbf2(lg[0][8 * kl + 6], lg[0][8 * kl + 7]);
      const unsigned int sa = hi ? p0a : p1a;
      const unsigned int sb = hi ? p0b : p1b;
      const unsigned int ra = __shfl_xor(sa, 32);
      const unsigned int rb = __shfl_xor(sb, 32);
      union { unsigned int w[4]; bf16x8 v; } u;
      u.w[0] = hi ? ra : p0a;
      u.w[1] = hi ? rb : p0b;
      u.w[2] = hi ? p1a : ra;
      u.w[3] = hi ? p1b : rb;
      pa[kl] = u.v;
    }
    __builtin_amdgcn_s_setprio(1);
#pragma unroll
    for (int cb = 0; cb < 2; ++cb) {
#pragma unroll
      for (int ks = 0; ks < 2; ++ks) {
        const bf16x8 vb = *(const bf16x8*)(Vls + off[cb][ks]);
        acc[cb] = __builtin_amdgcn_mfma_f32_32x32x16_bf16(vb, pa[ks], acc[cb],
                                                          0, 0, 0);
      }
    }
    __builtin_amdgcn_s_setprio(0);

    // ---- SM_1: exp2 on lg[1] (independent of PV_0 above -> co-issue) ----
    float ps1 = 0.f;
#pragma unroll
    for (int r = 0; r < 16; ++r) lg[1][r] = EXP2F(lg[1][r]);
#pragma unroll
    for (int r = 0; r < 8; ++r) ps1 += lg[1][2 * r] + lg[1][2 * r + 1];
    lsum += ps1;

    // ---- pack_1 + PV_1 (ks 2..3) ----
#pragma unroll
    for (int kl = 0; kl < 2; ++kl) {
      const unsigned int p0a = packbf2(lg[1][8 * kl + 0], lg[1][8 * kl + 1]);
      const unsigned int p0b = packbf2(lg[1][8 * kl + 2], lg[1][8 * kl + 3]);
      const unsigned int p1a = packbf2(lg[1][8 * kl + 4], lg[1][8 * kl + 5]);
      const unsigned int p1b = packbf2(lg[1][8 * kl + 6], lg[1][8 * kl + 7]);
      const unsigned int sa = hi ? p0a : p1a;
      const unsigned int sb = hi ? p0b : p1b;
      const unsigned int ra = __shfl_xor(sa, 32);
      const unsigned int rb = __shfl_xor(sb, 32);
      union { unsigned int w[4]; bf16x8 v; } u;
      u.w[0] = hi ? ra : p0a;
      u.w[1] = hi ? rb : p0b;
      u.w[2] = hi ? p1a : ra;
      u.w[3] = hi ? p1b : rb;
      pa[2 + kl] = u.v;
    }
    __builtin_amdgcn_s_setprio(1);
#pragma unroll
    for (int cb = 0; cb < 2; ++cb) {
#pragma unroll
      for (int ks = 2; ks < 4; ++ks) {
        const bf16x8 vb = *(const bf16x8*)(Vls + off[cb][ks]);
        acc[cb] = __builtin_amdgcn_mfma_f32_32x32x16_bf16(vb, pa[ks], acc[cb],
                                                          0, 0, 0);
      }
    }
    __builtin_amdgcn_s_setprio(0);
  }

  // ---- epilogue: normalize + store (D: col=t=lane&31, row=c) ----
  const float ls = fadd_x32(lsum);
  const float inv = 1.0f / ls;
#pragma unroll
  for (int cb = 0; cb < 2; ++cb) {
#pragma unroll
    for (int r = 0; r < 16; ++r) {
      const int c = cb * 32 + (r & 3) + 8 * (r >> 2) + 4 * hi;
      out[((size_t)bh * 64 + c) * 2048 + t0w + tl] = acc[cb][r] * inv;
    }
  }
}

extern "C" void kernel_launch(void* const* d_in, const int* in_sizes, int n_in,
                              void* d_out, int out_size, void* d_ws,
                              size_t ws_size, hipStream_t stream) {
  (void)in_sizes; (void)n_in; (void)out_size;
  const float* qkv = (const float*)d_in[0];
  float* out = (float*)d_out;
  const size_t kv_elems = (size_t)64 * 2048 * 64;
  if (ws_size < kv_elems * 2 * sizeof(short)) return;  // need 32 MB scratch
  short* Kt = (short*)d_ws;
  short* Vb = Kt + kv_elems;
  hipLaunchKernelGGL(qkv_prep_kernel, dim3(2048), dim3(256), 0, stream,
                     qkv, Kt, Vb);
  hipLaunchKernelGGL(attn32_kernel, dim3(512), dim3(512), 0, stream,
                     qkv, Kt, Vb, out);
}